// Round 4
// baseline (620.126 us; speedup 1.0000x reference)
//
#include <hip/hip_runtime.h>

typedef _Float16 f16;
typedef f16  half8 __attribute__((ext_vector_type(8)));
typedef float f32x4 __attribute__((ext_vector_type(4)));

#define B_   32
#define C_   1024
#define HW_  784
#define BQ   64
#define NCH  13   // ceil(784/64) k-chunks of 64

// ---------------------------------------------------------------------------
// Prep: m16[b][c][hw] = (f16)x, and mT[b][hw][c] = (f16)x transposed.
// ---------------------------------------------------------------------------
__global__ __launch_bounds__(256)
void prep_kernel(const float* __restrict__ x, f16* __restrict__ m16, f16* __restrict__ mT) {
  __shared__ f16 lt[64][72];
  const int bi = blockIdx.x;               // b*208 + ct*13 + ht
  const int ht = bi % 13;
  const int ct = (bi / 13) & 15;
  const int b  = bi / 208;
  const int h0 = ht * 64, c0 = ct * 64;
  const int t = threadIdx.x, r = t >> 2, q = t & 3;
  const size_t base = (size_t)b * (C_ * HW_);

  const int hq = h0 + q * 16;
  if (hq < HW_) {
    const float* src = x + base + (size_t)(c0 + r) * HW_ + hq;
    float f[16];
#pragma unroll
    for (int j = 0; j < 4; ++j) ((float4*)f)[j] = ((const float4*)src)[j];
    f16 h[16];
#pragma unroll
    for (int j = 0; j < 16; ++j) h[j] = (f16)f[j];
    f16* dm = m16 + base + (size_t)(c0 + r) * HW_ + hq;
    *(half8*)dm = *(half8*)h;
    *(half8*)(dm + 8) = *(half8*)(h + 8);
    *(half8*)&lt[r][q * 16]     = *(half8*)h;
    *(half8*)&lt[r][q * 16 + 8] = *(half8*)(h + 8);
  }
  __syncthreads();
  if (h0 + r < HW_) {
    f16 h[16];
#pragma unroll
    for (int j = 0; j < 16; ++j) h[j] = lt[q * 16 + j][r];
    f16* dst = mT + (size_t)b * (HW_ * C_) + (size_t)(h0 + r) * C_ + c0 + q * 16;
    *(half8*)dst = *(half8*)h;
    *(half8*)(dst + 8) = *(half8*)(h + 8);
  }
}

// ---------------------------------------------------------------------------
// Main: per WG = (batch, 64-row block), 16 waves.
// Phase 1: LDS-staged GEMM. B-tile [1024][64k] (128K, aliases P) + A-tile [64][64k]
//   (8K). Reg-staged with slot^=(row&7) swizzle -> conflict-light ds_read_b128.
// Boundary: P (raw f16 scores) written into the B-tile space; in-place softmax.
// Phase 2: y = P . V, si-outer/t-inner so V rows stream L1-resident.
// ---------------------------------------------------------------------------
__global__ __launch_bounds__(1024, 4)
void chanattn_main(const float* __restrict__ x, const f16* __restrict__ m16,
                   const f16* __restrict__ mT, float* __restrict__ out) {
  __shared__ __align__(128) char Lds[139264];  // [0,128K): B-tile / P alias; [128K,+8K): A-tile
  char* Bl = Lds;
  char* Al = Lds + 131072;
  char* Pb = Lds;

  const int bi   = blockIdx.x;
  const int slot = bi >> 3;
  const int b    = ((slot >> 4) << 3) | (bi & 7);   // same-batch WGs share an XCD
  const int rb   = slot & 15;
  const int q0   = rb * BQ;

  const int tid  = threadIdx.x;
  const int w    = tid >> 6;
  const int lane = tid & 63;
  const int l15  = lane & 15;
  const int l4   = lane >> 4;

  const f16* m16b = m16 + (size_t)b * (C_ * HW_);
  const f16* mTb  = mT  + (size_t)b * (HW_ * C_);

  // ---------------- Phase 1: staged GEMM, acc = M[q0..][.] . M^T ----------------
  f32x4 acc[4][4] = {};
  for (int kc = 0; kc < NCH; ++kc) {
    const int k0 = kc * 64;
    // stage B-tile: 1024 cols x 64 k  (8 x 16B per thread)
#pragma unroll
    for (int j = 0; j < 8; ++j) {
      const int sidx = j * 1024 + tid;
      const int col  = sidx >> 3, sl = sidx & 7;
      half8 v;
      if (k0 + sl * 8 + 8 <= HW_) v = *(const half8*)(m16b + (size_t)col * HW_ + k0 + sl * 8);
      else {
#pragma unroll
        for (int e = 0; e < 8; ++e) v[e] = (f16)0.f;
      }
      *(half8*)(Bl + col * 128 + ((sl ^ (col & 7)) << 4)) = v;
    }
    // stage A-tile: 64 rows x 64 k
    if (tid < 512) {
      const int r = tid >> 3, sl = tid & 7;
      half8 v;
      if (k0 + sl * 8 + 8 <= HW_) v = *(const half8*)(m16b + (size_t)(q0 + r) * HW_ + k0 + sl * 8);
      else {
#pragma unroll
        for (int e = 0; e < 8; ++e) v[e] = (f16)0.f;
      }
      *(half8*)(Al + r * 128 + ((sl ^ (r & 7)) << 4)) = v;
    }
    __syncthreads();
#pragma unroll
    for (int kf = 0; kf < 2; ++kf) {
      half8 afr[4], bfr[4];
#pragma unroll
      for (int rf = 0; rf < 4; ++rf) {
        const int r = rf * 16 + l15;
        afr[rf] = *(half8*)(Al + r * 128 + (((kf * 4 + l4) ^ (r & 7)) << 4));
      }
#pragma unroll
      for (int cf = 0; cf < 4; ++cf) {
        const int c = w * 64 + cf * 16 + l15;
        bfr[cf] = *(half8*)(Bl + c * 128 + (((kf * 4 + l4) ^ (c & 7)) << 4));
      }
#pragma unroll
      for (int rf = 0; rf < 4; ++rf)
#pragma unroll
        for (int cf = 0; cf < 4; ++cf)
          acc[rf][cf] = __builtin_amdgcn_mfma_f32_16x16x32_f16(afr[rf], bfr[cf], acc[rf][cf], 0, 0, 0);
    }
    __syncthreads();   // also protects the upcoming P-write aliasing B-tile
  }

  // write raw scores into P (aliases B-tile space; all reads done)
#pragma unroll
  for (int rf = 0; rf < 4; ++rf)
#pragma unroll
    for (int cf = 0; cf < 4; ++cf)
#pragma unroll
      for (int r = 0; r < 4; ++r) {
        const int row = rf * 16 + l4 * 4 + r;     // C/D: col=lane&15, row=(lane>>4)*4+reg
        const int col = w * 64 + cf * 16 + l15;
        int byte = row * 2048 + col * 2;
        byte ^= (row & 7) << 4;
        *(f16*)(Pb + byte) = (f16)acc[rf][cf][r];
      }
  __syncthreads();

  // ---------------- softmax, rows w*4..w*4+3 ----------------
  {
    const float ksc = 0.045084223f;   // log2(e)/32
    for (int rr = 0; rr < 4; ++rr) {
      const int row = w * 4 + rr;
      const int sw  = (row & 7) << 4;
      char* rbase = Pb + row * 2048;
      const int c0 = lane * 32;
      half8 v0 = *(half8*)(rbase + ((c0     ) ^ sw));
      half8 v1 = *(half8*)(rbase + ((c0 + 16) ^ sw));
      float f[16];
#pragma unroll
      for (int e = 0; e < 8; ++e) { f[e] = (float)v0[e]; f[e+8] = (float)v1[e]; }
      float mx = f[0];
#pragma unroll
      for (int e = 1; e < 16; ++e) mx = fmaxf(mx, f[e]);
      for (int d = 1; d < 64; d <<= 1) mx = fmaxf(mx, __shfl_xor(mx, d));
      float sum = 0.f;
#pragma unroll
      for (int e = 0; e < 16; ++e) { f[e] = exp2f((f[e] - mx) * ksc); sum += f[e]; }
      for (int d = 1; d < 64; d <<= 1) sum += __shfl_xor(sum, d);
      const float inv = 1.f / sum;
#pragma unroll
      for (int e = 0; e < 8; ++e) { v0[e] = (f16)(f[e]*inv); v1[e] = (f16)(f[e+8]*inv); }
      *(half8*)(rbase + ((c0     ) ^ sw)) = v0;
      *(half8*)(rbase + ((c0 + 16) ^ sw)) = v1;
    }
  }
  __syncthreads();

  // ---------------- Phase 2: y = P . V ; out = x + y (si outer, t inner) ----------------
#pragma unroll
  for (int si = 0; si < 4; ++si) {
    const int s = w + 16 * si;
    if (s < 49) {                       // wave-uniform
      const int d = s * 16 + l15;
      const f16* vrow = mTb + (size_t)d * C_;
      f32x4 a2[4] = {};
      for (int t = 0; t < 16; ++t) {
#pragma unroll
        for (int kf = 0; kf < 2; ++kf) {
          const half8 bfr = *(const half8*)(vrow + t * 64 + kf * 32 + l4 * 8);
#pragma unroll
          for (int rf = 0; rf < 4; ++rf) {
            const int row = rf * 16 + l15;          // A: row=lane&15, k=(lane>>4)*8+e
            int byte = row * 2048 + t * 128 + kf * 64 + (l4 << 4);
            byte ^= (row & 7) << 4;
            const half8 afr = *(half8*)(Pb + byte);
            a2[rf] = __builtin_amdgcn_mfma_f32_16x16x32_f16(afr, bfr, a2[rf], 0, 0, 0);
          }
        }
      }
#pragma unroll
      for (int rf = 0; rf < 4; ++rf)
#pragma unroll
        for (int r = 0; r < 4; ++r) {
          const size_t idx = (size_t)(b * C_ + q0 + rf * 16 + l4 * 4 + r) * HW_ + d;
          out[idx] = x[idx] + a2[rf][r];
        }
    }
  }
}

// ---------------------------------------------------------------------------
// Fallback (round-1 kernel): only if ws too small.
// ---------------------------------------------------------------------------
__device__ __forceinline__ half8 pack8(const float4& a, const float4& b) {
  half8 r;
  r[0]=(f16)a.x; r[1]=(f16)a.y; r[2]=(f16)a.z; r[3]=(f16)a.w;
  r[4]=(f16)b.x; r[5]=(f16)b.y; r[6]=(f16)b.z; r[7]=(f16)b.w;
  return r;
}

__global__ __launch_bounds__(512, 2)
void chanattn_fallback(const float* __restrict__ x, float* __restrict__ out) {
  __shared__ f16 Pl[BQ * C_];
  const int bi   = blockIdx.x;
  const int slot = bi >> 3;
  const int b    = ((slot >> 4) << 3) | (bi & 7);
  const int rb   = slot & 15;
  const int q0   = rb * BQ;
  const int tid  = threadIdx.x;
  const int w    = tid >> 6;
  const int lane = tid & 63;
  const int l15  = lane & 15;
  const int l4   = lane >> 4;
  const float* mb = x + (size_t)b * (C_ * HW_);
  char* Pb = (char*)Pl;
  {
    const int cw = w * 128;
    for (int tile = 0; tile < 2; ++tile) {
      const int c0 = cw + tile * 64;
      f32x4 acc[4][4] = {};
      for (int kc = 0; kc < 25; ++kc) {
        const int k0 = kc * 32 + l4 * 8;
        const bool ok = (k0 < HW_);
        half8 afr[4], bfr[4];
#pragma unroll
        for (int rf = 0; rf < 4; ++rf) {
          if (ok) { const float4* p = (const float4*)(mb + (q0 + rf*16 + l15) * HW_ + k0); afr[rf] = pack8(p[0], p[1]); }
          else {
#pragma unroll
            for (int e = 0; e < 8; ++e) afr[rf][e] = (f16)0.f; }
        }
#pragma unroll
        for (int cf = 0; cf < 4; ++cf) {
          if (ok) { const float4* p = (const float4*)(mb + (c0 + cf*16 + l15) * HW_ + k0); bfr[cf] = pack8(p[0], p[1]); }
          else {
#pragma unroll
            for (int e = 0; e < 8; ++e) bfr[cf][e] = (f16)0.f; }
        }
#pragma unroll
        for (int rf = 0; rf < 4; ++rf)
#pragma unroll
          for (int cf = 0; cf < 4; ++cf)
            acc[rf][cf] = __builtin_amdgcn_mfma_f32_16x16x32_f16(afr[rf], bfr[cf], acc[rf][cf], 0, 0, 0);
      }
#pragma unroll
      for (int rf = 0; rf < 4; ++rf)
#pragma unroll
        for (int cf = 0; cf < 4; ++cf)
#pragma unroll
          for (int r = 0; r < 4; ++r) {
            const int row = rf*16 + l4*4 + r;
            const int col = c0 + cf*16 + l15;
            int byte = row*2048 + col*2;
            byte ^= (row & 7) << 4;
            *(f16*)(Pb + byte) = (f16)acc[rf][cf][r];
          }
    }
  }
  __syncthreads();
  {
    const float ksc = 0.045084223f;
    for (int rr = 0; rr < 8; ++rr) {
      const int row = w*8 + rr;
      const int sw  = (row & 7) << 4;
      char* rbase = Pb + row*2048;
      const int c0 = lane * 32;
      half8 v0 = *(half8*)(rbase + ((c0     ) ^ sw));
      half8 v1 = *(half8*)(rbase + ((c0 + 16) ^ sw));
      float f[16];
#pragma unroll
      for (int e = 0; e < 8; ++e) { f[e] = (float)v0[e]; f[e+8] = (float)v1[e]; }
      float mx = f[0];
#pragma unroll
      for (int e = 1; e < 16; ++e) mx = fmaxf(mx, f[e]);
      for (int d = 1; d < 64; d <<= 1) mx = fmaxf(mx, __shfl_xor(mx, d));
      float sum = 0.f;
#pragma unroll
      for (int e = 0; e < 16; ++e) { f[e] = exp2f((f[e] - mx) * ksc); sum += f[e]; }
      for (int d = 1; d < 64; d <<= 1) sum += __shfl_xor(sum, d);
      const float inv = 1.f / sum;
#pragma unroll
      for (int e = 0; e < 8; ++e) { v0[e] = (f16)(f[e]*inv); v1[e] = (f16)(f[e+8]*inv); }
      *(half8*)(rbase + ((c0     ) ^ sw)) = v0;
      *(half8*)(rbase + ((c0 + 16) ^ sw)) = v1;
    }
  }
  __syncthreads();
  {
    f32x4 acc[7][4] = {};
    for (int t = 0; t < 16; ++t) {
      half8 afr[4][2];
#pragma unroll
      for (int rf = 0; rf < 4; ++rf)
#pragma unroll
        for (int kf = 0; kf < 2; ++kf) {
          const int row = rf*16 + l15;
          int byte = row*2048 + t*128 + kf*64 + l4*16;
          byte ^= (row & 7) << 4;
          afr[rf][kf] = *(half8*)(Pb + byte);
        }
#pragma unroll
      for (int si = 0; si < 7; ++si) {
        const int s = w + 8*si;
        if (s < 49) {
          const int d = s*16 + l15;
#pragma unroll
          for (int kf = 0; kf < 2; ++kf) {
            const int kv = t*64 + kf*32 + l4*8;
            half8 bfr;
#pragma unroll
            for (int e = 0; e < 8; ++e) bfr[e] = (f16)mb[(kv + e) * HW_ + d];
#pragma unroll
            for (int rf = 0; rf < 4; ++rf)
              acc[si][rf] = __builtin_amdgcn_mfma_f32_16x16x32_f16(afr[rf][kf], bfr, acc[si][rf], 0, 0, 0);
          }
        }
      }
    }
#pragma unroll
    for (int si = 0; si < 7; ++si) {
      const int s = w + 8*si;
      if (s < 49) {
        const int d = s*16 + l15;
#pragma unroll
        for (int rf = 0; rf < 4; ++rf)
#pragma unroll
          for (int r = 0; r < 4; ++r) {
            const size_t idx = (size_t)(b*C_ + q0 + rf*16 + l4*4 + r) * HW_ + d;
            out[idx] = x[idx] + acc[si][rf][r];
          }
      }
    }
  }
}

extern "C" void kernel_launch(void* const* d_in, const int* in_sizes, int n_in,
                              void* d_out, int out_size, void* d_ws, size_t ws_size,
                              hipStream_t stream) {
  const float* x = (const float*)d_in[0];
  float* out = (float*)d_out;
  const size_t elems = (size_t)B_ * C_ * HW_;          // 25,690,112
  const size_t need  = elems * 2 * 2;                  // m16 + mT (f16)
  if (ws_size >= need) {
    f16* m16 = (f16*)d_ws;
    f16* mT  = m16 + elems;
    prep_kernel<<<dim3(32 * 16 * 13), dim3(256), 0, stream>>>(x, m16, mT);
    chanattn_main<<<dim3(512), dim3(1024), 0, stream>>>(x, m16, mT, out);
  } else {
    chanattn_fallback<<<dim3(512), dim3(512), 0, stream>>>(x, out);
  }
}

// Round 5
// 557.750 us; speedup vs baseline: 1.1118x; 1.1118x over previous
//
#include <hip/hip_runtime.h>

typedef _Float16 f16;
typedef f16  half8 __attribute__((ext_vector_type(8)));
typedef float f32x4 __attribute__((ext_vector_type(4)));

#define B_   32
#define C_   1024
#define HW_  784
#define BQ   64
#define NCH  13   // k-chunks of 64 (last is tail: only k=768..783 valid)

// direct global->LDS DMA, 16B per lane (no VGPR round-trip)
__device__ __forceinline__ void gl_lds16(const f16* g, char* lds) {
  __builtin_amdgcn_global_load_lds((const __attribute__((address_space(1))) void*)g,
                                   (__attribute__((address_space(3))) void*)lds, 16, 0, 0);
}

// ---------------------------------------------------------------------------
// Prep: m16[b][c][hw] = (f16)x, and mT[b][hw][c] = (f16)x transposed.
// ---------------------------------------------------------------------------
__global__ __launch_bounds__(256)
void prep_kernel(const float* __restrict__ x, f16* __restrict__ m16, f16* __restrict__ mT) {
  __shared__ f16 lt[64][72];
  const int bi = blockIdx.x;               // b*208 + ct*13 + ht
  const int ht = bi % 13;
  const int ct = (bi / 13) & 15;
  const int b  = bi / 208;
  const int h0 = ht * 64, c0 = ct * 64;
  const int t = threadIdx.x, r = t >> 2, q = t & 3;
  const size_t base = (size_t)b * (C_ * HW_);

  const int hq = h0 + q * 16;
  if (hq < HW_) {
    const float* src = x + base + (size_t)(c0 + r) * HW_ + hq;
    float f[16];
#pragma unroll
    for (int j = 0; j < 4; ++j) ((float4*)f)[j] = ((const float4*)src)[j];
    f16 h[16];
#pragma unroll
    for (int j = 0; j < 16; ++j) h[j] = (f16)f[j];
    f16* dm = m16 + base + (size_t)(c0 + r) * HW_ + hq;
    *(half8*)dm = *(half8*)h;
    *(half8*)(dm + 8) = *(half8*)(h + 8);
    *(half8*)&lt[r][q * 16]     = *(half8*)h;
    *(half8*)&lt[r][q * 16 + 8] = *(half8*)(h + 8);
  }
  __syncthreads();
  if (h0 + r < HW_) {
    f16 h[16];
#pragma unroll
    for (int j = 0; j < 16; ++j) h[j] = lt[q * 16 + j][r];
    f16* dst = mT + (size_t)b * (HW_ * C_) + (size_t)(h0 + r) * C_ + c0 + q * 16;
    *(half8*)dst = *(half8*)h;
    *(half8*)(dst + 8) = *(half8*)(h + 8);
  }
}

// ---------------------------------------------------------------------------
// Main: per WG = (batch, 64-row block), 16 waves.
// Phase 1: LDS-staged GEMM via global_load_lds DMA (no staging VGPRs).
//   B-tile [1024 cols][64 k] = 128K (aliases P), A-tile [64][64 k] = 8K.
//   Swizzle done on the global SOURCE address (LDS dest stays linear):
//   lane l of chunk ch covers col=ch*8+(l>>3), phys slot s=l&7, and fetches
//   global k-slot (l&7)^((l>>3)&7)  ==  s ^ (col&7).
// Boundary: raw f16 scores -> P (aliases B); conflict-free in-place softmax.
// Phase 2: y = P . V, si-outer/t-inner so V rows stream L1-resident.
// ---------------------------------------------------------------------------
__global__ __launch_bounds__(1024, 4)
void chanattn_main(const float* __restrict__ x, const f16* __restrict__ m16,
                   const f16* __restrict__ mT, float* __restrict__ out) {
  __shared__ __align__(128) char Lds[139264];  // [0,128K): B-tile / P alias; [128K,+8K): A-tile
  char* Bl = Lds;
  char* Al = Lds + 131072;
  char* Pb = Lds;

  const int bi   = blockIdx.x;
  const int slot = bi >> 3;
  const int b    = ((slot >> 4) << 3) | (bi & 7);   // same-batch WGs share an XCD
  const int rb   = slot & 15;
  const int q0   = rb * BQ;

  const int tid  = threadIdx.x;
  const int w    = tid >> 6;
  const int lane = tid & 63;
  const int l15  = lane & 15;
  const int l4   = lane >> 4;

  const f16* m16b = m16 + (size_t)b * (C_ * HW_);
  const f16* mTb  = mT  + (size_t)b * (HW_ * C_);

  // per-lane source swizzle pieces (constant across chunks)
  const int lcol8 = lane >> 3;                       // col offset within chunk
  const int gsl   = (lane & 7) ^ (lcol8 & 7);        // global k-slot for this lane

  // ---------------- Phase 1: staged GEMM, acc = M[q0..][.] . M^T ----------------
  f32x4 acc[4][4] = {};
  for (int kc = 0; kc < NCH; ++kc) {
    const int k0 = kc * 64;
    const bool tail = (kc == NCH - 1);
    if (tail) {
      // zero A-tile so k>=784 contributions vanish (stale B x zero A = 0)
      *(float2*)(Al + tid * 8) = make_float2(0.f, 0.f);
      __syncthreads();
    }
    // stage B-tile: 128 chunks of 1KB; wave w takes chunks j*16+w
#pragma unroll
    for (int j = 0; j < 8; ++j) {
      const int ch  = j * 16 + w;
      const int col = ch * 8 + lcol8;
      const f16* g  = m16b + (size_t)col * HW_ + k0 + gsl * 8;
      char* dst     = Bl + ch * 1024 + lane * 16;
      if (!tail || gsl < 2) gl_lds16(g, dst);
    }
    // stage A-tile: 8 chunks; waves 0..7
    if (w < 8) {
      const int r  = w * 8 + lcol8;
      const f16* g = m16b + (size_t)(q0 + r) * HW_ + k0 + gsl * 8;
      char* dst    = Al + w * 1024 + lane * 16;
      if (!tail || gsl < 2) gl_lds16(g, dst);
    }
    __syncthreads();   // drains vmcnt (DMA) before reads
#pragma unroll
    for (int kf = 0; kf < 2; ++kf) {
      half8 afr[4], bfr[4];
#pragma unroll
      for (int rf = 0; rf < 4; ++rf) {
        const int r = rf * 16 + l15;
        afr[rf] = *(half8*)(Al + r * 128 + (((kf * 4 + l4) ^ (r & 7)) << 4));
      }
#pragma unroll
      for (int cf = 0; cf < 4; ++cf) {
        const int c = w * 64 + cf * 16 + l15;
        bfr[cf] = *(half8*)(Bl + c * 128 + (((kf * 4 + l4) ^ (c & 7)) << 4));
      }
#pragma unroll
      for (int rf = 0; rf < 4; ++rf)
#pragma unroll
        for (int cf = 0; cf < 4; ++cf)
          acc[rf][cf] = __builtin_amdgcn_mfma_f32_16x16x32_f16(afr[rf], bfr[cf], acc[rf][cf], 0, 0, 0);
    }
    __syncthreads();   // protects next-chunk staging (and final P-write alias)
  }

  // write raw scores into P (aliases B-tile space)
#pragma unroll
  for (int rf = 0; rf < 4; ++rf)
#pragma unroll
    for (int cf = 0; cf < 4; ++cf)
#pragma unroll
      for (int r = 0; r < 4; ++r) {
        const int row = rf * 16 + l4 * 4 + r;     // C/D: col=lane&15, row=(lane>>4)*4+reg
        const int col = w * 64 + cf * 16 + l15;
        int byte = row * 2048 + col * 2;
        byte ^= (row & 7) << 4;
        *(f16*)(Pb + byte) = (f16)acc[rf][cf][r];
      }
  __syncthreads();

  // ---------------- softmax, rows w*4..w*4+3 (consecutive-16B lanes) ----------------
  {
    const float ksc = 0.045084223f;   // log2(e)/32
    for (int rr = 0; rr < 4; ++rr) {
      const int row = w * 4 + rr;
      const int sw  = (row & 7) << 4;
      char* rbase = Pb + row * 2048;
      const int p0 = (lane * 16) ^ sw;           // conflict-free: lane-consecutive 16B
      half8 v0 = *(half8*)(rbase + p0);
      half8 v1 = *(half8*)(rbase + 1024 + p0);
      float f[16];
#pragma unroll
      for (int e = 0; e < 8; ++e) { f[e] = (float)v0[e]; f[e+8] = (float)v1[e]; }
      float mx = f[0];
#pragma unroll
      for (int e = 1; e < 16; ++e) mx = fmaxf(mx, f[e]);
      for (int d = 1; d < 64; d <<= 1) mx = fmaxf(mx, __shfl_xor(mx, d));
      float sum = 0.f;
#pragma unroll
      for (int e = 0; e < 16; ++e) { f[e] = exp2f((f[e] - mx) * ksc); sum += f[e]; }
      for (int d = 1; d < 64; d <<= 1) sum += __shfl_xor(sum, d);
      const float inv = 1.f / sum;
#pragma unroll
      for (int e = 0; e < 8; ++e) { v0[e] = (f16)(f[e]*inv); v1[e] = (f16)(f[e+8]*inv); }
      *(half8*)(rbase + p0) = v0;
      *(half8*)(rbase + 1024 + p0) = v1;
    }
  }
  __syncthreads();

  // ---------------- Phase 2: y = P . V ; out = x + y (si outer, t inner) ----------------
#pragma unroll
  for (int si = 0; si < 4; ++si) {
    const int s = w + 16 * si;
    if (s < 49) {                       // wave-uniform
      const int d = s * 16 + l15;
      const f16* vrow = mTb + (size_t)d * C_;
      f32x4 a2[4] = {};
      for (int t = 0; t < 16; ++t) {
#pragma unroll
        for (int kf = 0; kf < 2; ++kf) {
          const half8 bfr = *(const half8*)(vrow + t * 64 + kf * 32 + l4 * 8);
#pragma unroll
          for (int rf = 0; rf < 4; ++rf) {
            const int row = rf * 16 + l15;          // A: row=lane&15, k=(lane>>4)*8+e
            int byte = row * 2048 + t * 128 + kf * 64 + (l4 << 4);
            byte ^= (row & 7) << 4;
            const half8 afr = *(half8*)(Pb + byte);
            a2[rf] = __builtin_amdgcn_mfma_f32_16x16x32_f16(afr, bfr, a2[rf], 0, 0, 0);
          }
        }
      }
#pragma unroll
      for (int rf = 0; rf < 4; ++rf)
#pragma unroll
        for (int r = 0; r < 4; ++r) {
          const size_t idx = (size_t)(b * C_ + q0 + rf * 16 + l4 * 4 + r) * HW_ + d;
          out[idx] = x[idx] + a2[rf][r];
        }
    }
  }
}

// ---------------------------------------------------------------------------
// Fallback (round-1 kernel): only if ws too small.
// ---------------------------------------------------------------------------
__device__ __forceinline__ half8 pack8(const float4& a, const float4& b) {
  half8 r;
  r[0]=(f16)a.x; r[1]=(f16)a.y; r[2]=(f16)a.z; r[3]=(f16)a.w;
  r[4]=(f16)b.x; r[5]=(f16)b.y; r[6]=(f16)b.z; r[7]=(f16)b.w;
  return r;
}

__global__ __launch_bounds__(512, 2)
void chanattn_fallback(const float* __restrict__ x, float* __restrict__ out) {
  __shared__ f16 Pl[BQ * C_];
  const int bi   = blockIdx.x;
  const int slot = bi >> 3;
  const int b    = ((slot >> 4) << 3) | (bi & 7);
  const int rb   = slot & 15;
  const int q0   = rb * BQ;
  const int tid  = threadIdx.x;
  const int w    = tid >> 6;
  const int lane = tid & 63;
  const int l15  = lane & 15;
  const int l4   = lane >> 4;
  const float* mb = x + (size_t)b * (C_ * HW_);
  char* Pb = (char*)Pl;
  {
    const int cw = w * 128;
    for (int tile = 0; tile < 2; ++tile) {
      const int c0 = cw + tile * 64;
      f32x4 acc[4][4] = {};
      for (int kc = 0; kc < 25; ++kc) {
        const int k0 = kc * 32 + l4 * 8;
        const bool ok = (k0 < HW_);
        half8 afr[4], bfr[4];
#pragma unroll
        for (int rf = 0; rf < 4; ++rf) {
          if (ok) { const float4* p = (const float4*)(mb + (q0 + rf*16 + l15) * HW_ + k0); afr[rf] = pack8(p[0], p[1]); }
          else {
#pragma unroll
            for (int e = 0; e < 8; ++e) afr[rf][e] = (f16)0.f; }
        }
#pragma unroll
        for (int cf = 0; cf < 4; ++cf) {
          if (ok) { const float4* p = (const float4*)(mb + (c0 + cf*16 + l15) * HW_ + k0); bfr[cf] = pack8(p[0], p[1]); }
          else {
#pragma unroll
            for (int e = 0; e < 8; ++e) bfr[cf][e] = (f16)0.f; }
        }
#pragma unroll
        for (int rf = 0; rf < 4; ++rf)
#pragma unroll
          for (int cf = 0; cf < 4; ++cf)
            acc[rf][cf] = __builtin_amdgcn_mfma_f32_16x16x32_f16(afr[rf], bfr[cf], acc[rf][cf], 0, 0, 0);
      }
#pragma unroll
      for (int rf = 0; rf < 4; ++rf)
#pragma unroll
        for (int cf = 0; cf < 4; ++cf)
#pragma unroll
          for (int r = 0; r < 4; ++r) {
            const int row = rf*16 + l4*4 + r;
            const int col = c0 + cf*16 + l15;
            int byte = row*2048 + col*2;
            byte ^= (row & 7) << 4;
            *(f16*)(Pb + byte) = (f16)acc[rf][cf][r];
          }
    }
  }
  __syncthreads();
  {
    const float ksc = 0.045084223f;
    for (int rr = 0; rr < 8; ++rr) {
      const int row = w*8 + rr;
      const int sw  = (row & 7) << 4;
      char* rbase = Pb + row*2048;
      const int p0 = (lane * 16) ^ sw;
      half8 v0 = *(half8*)(rbase + p0);
      half8 v1 = *(half8*)(rbase + 1024 + p0);
      float f[16];
#pragma unroll
      for (int e = 0; e < 8; ++e) { f[e] = (float)v0[e]; f[e+8] = (float)v1[e]; }
      float mx = f[0];
#pragma unroll
      for (int e = 1; e < 16; ++e) mx = fmaxf(mx, f[e]);
      for (int d = 1; d < 64; d <<= 1) mx = fmaxf(mx, __shfl_xor(mx, d));
      float sum = 0.f;
#pragma unroll
      for (int e = 0; e < 16; ++e) { f[e] = exp2f((f[e] - mx) * ksc); sum += f[e]; }
      for (int d = 1; d < 64; d <<= 1) sum += __shfl_xor(sum, d);
      const float inv = 1.f / sum;
#pragma unroll
      for (int e = 0; e < 8; ++e) { v0[e] = (f16)(f[e]*inv); v1[e] = (f16)(f[e+8]*inv); }
      *(half8*)(rbase + p0) = v0;
      *(half8*)(rbase + 1024 + p0) = v1;
    }
  }
  __syncthreads();
  {
    f32x4 acc[7][4] = {};
    for (int t = 0; t < 16; ++t) {
      half8 afr[4][2];
#pragma unroll
      for (int rf = 0; rf < 4; ++rf)
#pragma unroll
        for (int kf = 0; kf < 2; ++kf) {
          const int row = rf*16 + l15;
          int byte = row*2048 + t*128 + kf*64 + l4*16;
          byte ^= (row & 7) << 4;
          afr[rf][kf] = *(half8*)(Pb + byte);
        }
#pragma unroll
      for (int si = 0; si < 7; ++si) {
        const int s = w + 8*si;
        if (s < 49) {
          const int d = s*16 + l15;
#pragma unroll
          for (int kf = 0; kf < 2; ++kf) {
            const int kv = t*64 + kf*32 + l4*8;
            half8 bfr;
#pragma unroll
            for (int e = 0; e < 8; ++e) bfr[e] = (f16)mb[(kv + e) * HW_ + d];
#pragma unroll
            for (int rf = 0; rf < 4; ++rf)
              acc[si][rf] = __builtin_amdgcn_mfma_f32_16x16x32_f16(afr[rf][kf], bfr, acc[si][rf], 0, 0, 0);
          }
        }
      }
    }
#pragma unroll
    for (int si = 0; si < 7; ++si) {
      const int s = w + 8*si;
      if (s < 49) {
        const int d = s*16 + l15;
#pragma unroll
        for (int rf = 0; rf < 4; ++rf)
#pragma unroll
          for (int r = 0; r < 4; ++r) {
            const size_t idx = (size_t)(b*C_ + q0 + rf*16 + l4*4 + r) * HW_ + d;
            out[idx] = x[idx] + acc[si][rf][r];
          }
      }
    }
  }
}

extern "C" void kernel_launch(void* const* d_in, const int* in_sizes, int n_in,
                              void* d_out, int out_size, void* d_ws, size_t ws_size,
                              hipStream_t stream) {
  const float* x = (const float*)d_in[0];
  float* out = (float*)d_out;
  const size_t elems = (size_t)B_ * C_ * HW_;          // 25,690,112
  const size_t need  = elems * 2 * 2;                  // m16 + mT (f16)
  if (ws_size >= need) {
    f16* m16 = (f16*)d_ws;
    f16* mT  = m16 + elems;
    prep_kernel<<<dim3(32 * 16 * 13), dim3(256), 0, stream>>>(x, m16, mT);
    chanattn_main<<<dim3(512), dim3(1024), 0, stream>>>(x, m16, mT, out);
  } else {
    chanattn_fallback<<<dim3(512), dim3(512), 0, stream>>>(x, out);
  }
}

// Round 6
// 195.090 us; speedup vs baseline: 3.1787x; 2.8589x over previous
//
#include <hip/hip_runtime.h>

typedef _Float16 f16;
typedef f16  half8 __attribute__((ext_vector_type(8)));
typedef float f32x4 __attribute__((ext_vector_type(4)));

#define B_   32
#define C_   1024
#define HW_  784
#define BQ   64

// Fragment-packed workspace layouts (offsets in f16 elements):
//  mA   [b][panel=c>>4][kc=0..23][lane]  half8 along k=kc*32+(lane>>4)*8, row c=panel*16+(lane&15)
//  tailA[b][panel][sl=0..1][l15]         half8 along k=768+sl*8 (valid lanes l4<2)
//  mV   [b][pd=d>>4][kt=kv>>5][lane]     half8 along kv=kt*32+(lane>>4)*8, row d=pd*16+(lane&15)
#define MA_BATCH  786432ull        // 64*24*512
#define TA_OFF    25165824ull      // 32*MA_BATCH
#define TA_BATCH  16384ull         // 64*2*16*8
#define MV_OFF    25690112ull      // TA_OFF + 32*TA_BATCH
#define MV_BATCH  802816ull        // 49*32*512
// total = (MV_OFF + 32*MV_BATCH)*2 = 102,760,448 bytes (== proven-available ws)

// ---------------------------------------------------------------------------
// Prep: build mA / tailA / mV from x (f32 -> f16, fragment-packed).
// ---------------------------------------------------------------------------
__global__ __launch_bounds__(256)
void prep_kernel(const float* __restrict__ x, f16* __restrict__ ws) {
  __shared__ f16 lt[64][72];   // padded transpose tile
  const int bi = blockIdx.x;               // b*208 + ct*13 + ht
  const int ht = bi % 13;
  const int ct = (bi / 13) & 15;
  const int b  = bi / 208;
  const int h0 = ht * 64, c0 = ct * 64;
  const int t = threadIdx.x, r = t >> 2, q = t & 3;

  f16* mA = ws + (size_t)b * MA_BATCH;
  f16* tA = ws + TA_OFF + (size_t)b * TA_BATCH;
  f16* mV = ws + MV_OFF + (size_t)b * MV_BATCH;

  const int c  = c0 + r;
  const int pc = c >> 4, cl = c & 15;
  const int hq = h0 + q * 16;
  if (hq < HW_) {
    const float* src = x + (size_t)b * (C_ * HW_) + (size_t)c * HW_ + hq;
    float f[16];
#pragma unroll
    for (int j = 0; j < 4; ++j) ((float4*)f)[j] = ((const float4*)src)[j];
    f16 h[16];
#pragma unroll
    for (int j = 0; j < 16; ++j) h[j] = (f16)f[j];
    if (hq < 768) {
      const int kc = hq >> 5;
      const int l4 = (hq >> 3) & 3;          // 0 or 2
      f16* d0 = mA + ((size_t)pc * 24 + kc) * 512 + ((l4    ) * 16 + cl) * 8;
      f16* d1 = mA + ((size_t)pc * 24 + kc) * 512 + ((l4 + 1) * 16 + cl) * 8;
      *(half8*)d0 = *(half8*)h;
      *(half8*)d1 = *(half8*)(h + 8);
    } else {                                  // hq == 768: tail chunk
      f16* d0 = tA + pc * 256 + cl * 8;
      f16* d1 = tA + pc * 256 + 128 + cl * 8;
      *(half8*)d0 = *(half8*)h;
      *(half8*)d1 = *(half8*)(h + 8);
    }
    *(half8*)&lt[r][q * 16]     = *(half8*)h;
    *(half8*)&lt[r][q * 16 + 8] = *(half8*)(h + 8);
  }
  __syncthreads();
  // transposed side -> mV (d = hw, kv = c)
  if (h0 + r < HW_) {
    f16 g[16];
#pragma unroll
    for (int j = 0; j < 16; ++j) g[j] = lt[q * 16 + j][r];
    const int d  = h0 + r;
    const int pd = d >> 4, dl = d & 15;
    const int kv = c0 + q * 16;
    const int kt = kv >> 5;
    const int l4 = (kv >> 3) & 3;            // 0 or 2
    f16* e0 = mV + ((size_t)pd * 32 + kt) * 512 + ((l4    ) * 16 + dl) * 8;
    f16* e1 = mV + ((size_t)pd * 32 + kt) * 512 + ((l4 + 1) * 16 + dl) * 8;
    *(half8*)e0 = *(half8*)g;
    *(half8*)e1 = *(half8*)(g + 8);
  }
}

// ---------------------------------------------------------------------------
// Main (round-3 structure, fragment-packed coalesced loads).
// ---------------------------------------------------------------------------
__global__ __launch_bounds__(1024, 4)
void chanattn_main(const float* __restrict__ x, const f16* __restrict__ ws,
                   float* __restrict__ out) {
  __shared__ f16 Pl[BQ * C_];   // 128 KiB
  char* Pb = (char*)Pl;

  const int bi   = blockIdx.x;
  const int slot = bi >> 3;
  const int b    = ((slot >> 4) << 3) | (bi & 7);   // same-batch WGs share an XCD
  const int rb   = slot & 15;
  const int q0   = rb * BQ;

  const int tid  = threadIdx.x;
  const int w    = tid >> 6;    // 0..15
  const int lane = tid & 63;
  const int l15  = lane & 15;
  const int l4   = lane >> 4;

  const f16* mA = ws + (size_t)b * MA_BATCH;
  const f16* tA = ws + TA_OFF + (size_t)b * TA_BATCH;
  const f16* mV = ws + MV_OFF + (size_t)b * MV_BATCH;

  const int pa = q0 >> 4;       // A panel base (rb*4)

  // ---------------- Phase 1: raw scores (wave w -> cols w*64..w*64+63) ----------------
  {
    f32x4 acc[4][4] = {};
    for (int kc = 0; kc < 24; ++kc) {
      half8 afr[4], bfr[4];
#pragma unroll
      for (int rf = 0; rf < 4; ++rf)
        afr[rf] = *(const half8*)(mA + ((size_t)(pa + rf) * 24 + kc) * 512 + lane * 8);
#pragma unroll
      for (int cf = 0; cf < 4; ++cf)
        bfr[cf] = *(const half8*)(mA + ((size_t)(w * 4 + cf) * 24 + kc) * 512 + lane * 8);
#pragma unroll
      for (int rf = 0; rf < 4; ++rf)
#pragma unroll
        for (int cf = 0; cf < 4; ++cf)
          acc[rf][cf] = __builtin_amdgcn_mfma_f32_16x16x32_f16(afr[rf], bfr[cf], acc[rf][cf], 0, 0, 0);
    }
    // tail chunk k=768..783 (zero for l4>=2)
    {
      half8 afr[4], bfr[4];
#pragma unroll
      for (int rf = 0; rf < 4; ++rf) {
        half8 v = {};
        if (l4 < 2) v = *(const half8*)(tA + (pa + rf) * 256 + lane * 8);
        afr[rf] = v;
      }
#pragma unroll
      for (int cf = 0; cf < 4; ++cf) {
        half8 v = {};
        if (l4 < 2) v = *(const half8*)(tA + (w * 4 + cf) * 256 + lane * 8);
        bfr[cf] = v;
      }
#pragma unroll
      for (int rf = 0; rf < 4; ++rf)
#pragma unroll
        for (int cf = 0; cf < 4; ++cf)
          acc[rf][cf] = __builtin_amdgcn_mfma_f32_16x16x32_f16(afr[rf], bfr[cf], acc[rf][cf], 0, 0, 0);
    }
    // write raw scores -> P (XOR swizzle)
#pragma unroll
    for (int rf = 0; rf < 4; ++rf)
#pragma unroll
      for (int cf = 0; cf < 4; ++cf)
#pragma unroll
        for (int r = 0; r < 4; ++r) {
          const int row = rf * 16 + l4 * 4 + r;     // C/D: col=lane&15, row=(lane>>4)*4+reg
          const int col = w * 64 + cf * 16 + l15;
          int byte = row * 2048 + col * 2;
          byte ^= (row & 7) << 4;
          *(f16*)(Pb + byte) = (f16)acc[rf][cf][r];
        }
  }
  __syncthreads();

  // ---------------- softmax, rows w*4..w*4+3 (lane-consecutive 16B) ----------------
  {
    const float ksc = 0.045084223f;   // log2(e)/32
    for (int rr = 0; rr < 4; ++rr) {
      const int row = w * 4 + rr;
      const int sw  = (row & 7) << 4;
      char* rbase = Pb + row * 2048;
      const int p0 = (lane * 16) ^ sw;
      half8 v0 = *(half8*)(rbase + p0);
      half8 v1 = *(half8*)(rbase + 1024 + p0);
      float f[16];
#pragma unroll
      for (int e = 0; e < 8; ++e) { f[e] = (float)v0[e]; f[e+8] = (float)v1[e]; }
      float mx = f[0];
#pragma unroll
      for (int e = 1; e < 16; ++e) mx = fmaxf(mx, f[e]);
      for (int d = 1; d < 64; d <<= 1) mx = fmaxf(mx, __shfl_xor(mx, d));
      float sum = 0.f;
#pragma unroll
      for (int e = 0; e < 16; ++e) { f[e] = exp2f((f[e] - mx) * ksc); sum += f[e]; }
      for (int d = 1; d < 64; d <<= 1) sum += __shfl_xor(sum, d);
      const float inv = 1.f / sum;
#pragma unroll
      for (int e = 0; e < 8; ++e) { v0[e] = (f16)(f[e]*inv); v1[e] = (f16)(f[e+8]*inv); }
      *(half8*)(rbase + p0) = v0;
      *(half8*)(rbase + 1024 + p0) = v1;
    }
  }
  __syncthreads();

  // ---------------- Phase 2: y = P . V ; out = x + y (t outer) ----------------
  {
    f32x4 a2[4][4] = {};   // [si][rf]
    for (int t = 0; t < 16; ++t) {
      half8 afr[4][2];
#pragma unroll
      for (int rf = 0; rf < 4; ++rf)
#pragma unroll
        for (int kf = 0; kf < 2; ++kf) {
          const int row = rf * 16 + l15;            // A: row=lane&15, k=(lane>>4)*8+e
          int byte = row * 2048 + t * 128 + kf * 64 + (l4 << 4);
          byte ^= (row & 7) << 4;
          afr[rf][kf] = *(half8*)(Pb + byte);
        }
#pragma unroll
      for (int si = 0; si < 4; ++si) {
        const int s = w + 16 * si;
        if (s < 49) {                               // wave-uniform
#pragma unroll
          for (int kf = 0; kf < 2; ++kf) {
            const half8 bfr = *(const half8*)(mV + ((size_t)s * 32 + t * 2 + kf) * 512 + lane * 8);
#pragma unroll
            for (int rf = 0; rf < 4; ++rf)
              a2[si][rf] = __builtin_amdgcn_mfma_f32_16x16x32_f16(afr[rf][kf], bfr, a2[si][rf], 0, 0, 0);
          }
        }
      }
    }
#pragma unroll
    for (int si = 0; si < 4; ++si) {
      const int s = w + 16 * si;
      if (s < 49) {
        const int d = s * 16 + l15;
#pragma unroll
        for (int rf = 0; rf < 4; ++rf)
#pragma unroll
          for (int r = 0; r < 4; ++r) {
            const size_t idx = (size_t)(b * C_ + q0 + rf * 16 + l4 * 4 + r) * HW_ + d;
            out[idx] = x[idx] + a2[si][rf][r];
          }
      }
    }
  }
}

// ---------------------------------------------------------------------------
// Fallback (round-1 kernel): only if ws too small.
// ---------------------------------------------------------------------------
__device__ __forceinline__ half8 pack8(const float4& a, const float4& b) {
  half8 r;
  r[0]=(f16)a.x; r[1]=(f16)a.y; r[2]=(f16)a.z; r[3]=(f16)a.w;
  r[4]=(f16)b.x; r[5]=(f16)b.y; r[6]=(f16)b.z; r[7]=(f16)b.w;
  return r;
}

__global__ __launch_bounds__(512, 2)
void chanattn_fallback(const float* __restrict__ x, float* __restrict__ out) {
  __shared__ f16 Pl[BQ * C_];
  const int bi   = blockIdx.x;
  const int slot = bi >> 3;
  const int b    = ((slot >> 4) << 3) | (bi & 7);
  const int rb   = slot & 15;
  const int q0   = rb * BQ;
  const int tid  = threadIdx.x;
  const int w    = tid >> 6;
  const int lane = tid & 63;
  const int l15  = lane & 15;
  const int l4   = lane >> 4;
  const float* mb = x + (size_t)b * (C_ * HW_);
  char* Pb = (char*)Pl;
  {
    const int cw = w * 128;
    for (int tile = 0; tile < 2; ++tile) {
      const int c0 = cw + tile * 64;
      f32x4 acc[4][4] = {};
      for (int kc = 0; kc < 25; ++kc) {
        const int k0 = kc * 32 + l4 * 8;
        const bool ok = (k0 < HW_);
        half8 afr[4], bfr[4];
#pragma unroll
        for (int rf = 0; rf < 4; ++rf) {
          if (ok) { const float4* p = (const float4*)(mb + (q0 + rf*16 + l15) * HW_ + k0); afr[rf] = pack8(p[0], p[1]); }
          else {
#pragma unroll
            for (int e = 0; e < 8; ++e) afr[rf][e] = (f16)0.f; }
        }
#pragma unroll
        for (int cf = 0; cf < 4; ++cf) {
          if (ok) { const float4* p = (const float4*)(mb + (c0 + cf*16 + l15) * HW_ + k0); bfr[cf] = pack8(p[0], p[1]); }
          else {
#pragma unroll
            for (int e = 0; e < 8; ++e) bfr[cf][e] = (f16)0.f; }
        }
#pragma unroll
        for (int rf = 0; rf < 4; ++rf)
#pragma unroll
          for (int cf = 0; cf < 4; ++cf)
            acc[rf][cf] = __builtin_amdgcn_mfma_f32_16x16x32_f16(afr[rf], bfr[cf], acc[rf][cf], 0, 0, 0);
      }
#pragma unroll
      for (int rf = 0; rf < 4; ++rf)
#pragma unroll
        for (int cf = 0; cf < 4; ++cf)
#pragma unroll
          for (int r = 0; r < 4; ++r) {
            const int row = rf*16 + l4*4 + r;
            const int col = c0 + cf*16 + l15;
            int byte = row*2048 + col*2;
            byte ^= (row & 7) << 4;
            *(f16*)(Pb + byte) = (f16)acc[rf][cf][r];
          }
    }
  }
  __syncthreads();
  {
    const float ksc = 0.045084223f;
    for (int rr = 0; rr < 8; ++rr) {
      const int row = w*8 + rr;
      const int sw  = (row & 7) << 4;
      char* rbase = Pb + row*2048;
      const int p0 = (lane * 16) ^ sw;
      half8 v0 = *(half8*)(rbase + p0);
      half8 v1 = *(half8*)(rbase + 1024 + p0);
      float f[16];
#pragma unroll
      for (int e = 0; e < 8; ++e) { f[e] = (float)v0[e]; f[e+8] = (float)v1[e]; }
      float mx = f[0];
#pragma unroll
      for (int e = 1; e < 16; ++e) mx = fmaxf(mx, f[e]);
      for (int d = 1; d < 64; d <<= 1) mx = fmaxf(mx, __shfl_xor(mx, d));
      float sum = 0.f;
#pragma unroll
      for (int e = 0; e < 16; ++e) { f[e] = exp2f((f[e] - mx) * ksc); sum += f[e]; }
      for (int d = 1; d < 64; d <<= 1) sum += __shfl_xor(sum, d);
      const float inv = 1.f / sum;
#pragma unroll
      for (int e = 0; e < 8; ++e) { v0[e] = (f16)(f[e]*inv); v1[e] = (f16)(f[e+8]*inv); }
      *(half8*)(rbase + p0) = v0;
      *(half8*)(rbase + 1024 + p0) = v1;
    }
  }
  __syncthreads();
  {
    f32x4 acc[7][4] = {};
    for (int t = 0; t < 16; ++t) {
      half8 afr[4][2];
#pragma unroll
      for (int rf = 0; rf < 4; ++rf)
#pragma unroll
        for (int kf = 0; kf < 2; ++kf) {
          const int row = rf*16 + l15;
          int byte = row*2048 + t*128 + kf*64 + l4*16;
          byte ^= (row & 7) << 4;
          afr[rf][kf] = *(half8*)(Pb + byte);
        }
#pragma unroll
      for (int si = 0; si < 7; ++si) {
        const int s = w + 8*si;
        if (s < 49) {
          const int d = s*16 + l15;
#pragma unroll
          for (int kf = 0; kf < 2; ++kf) {
            const int kv = t*64 + kf*32 + l4*8;
            half8 bfr;
#pragma unroll
            for (int e = 0; e < 8; ++e) bfr[e] = (f16)mb[(kv + e) * HW_ + d];
#pragma unroll
            for (int rf = 0; rf < 4; ++rf)
              acc[si][rf] = __builtin_amdgcn_mfma_f32_16x16x32_f16(afr[rf][kf], bfr, acc[si][rf], 0, 0, 0);
          }
        }
      }
    }
#pragma unroll
    for (int si = 0; si < 7; ++si) {
      const int s = w + 8*si;
      if (s < 49) {
        const int d = s*16 + l15;
#pragma unroll
        for (int rf = 0; rf < 4; ++rf)
#pragma unroll
          for (int r = 0; r < 4; ++r) {
            const size_t idx = (size_t)(b*C_ + q0 + rf*16 + l4*4 + r) * HW_ + d;
            out[idx] = x[idx] + acc[si][rf][r];
          }
      }
    }
  }
}

extern "C" void kernel_launch(void* const* d_in, const int* in_sizes, int n_in,
                              void* d_out, int out_size, void* d_ws, size_t ws_size,
                              hipStream_t stream) {
  const float* x = (const float*)d_in[0];
  float* out = (float*)d_out;
  const size_t need = (MV_OFF + 32ull * MV_BATCH) * 2;   // 102,760,448 B
  if (ws_size >= need) {
    f16* ws = (f16*)d_ws;
    prep_kernel<<<dim3(32 * 16 * 13), dim3(256), 0, stream>>>(x, ws);
    chanattn_main<<<dim3(512), dim3(1024), 0, stream>>>(x, ws, out);
  } else {
    chanattn_fallback<<<dim3(512), dim3(512), 0, stream>>>(x, out);
  }
}